// Round 2
// baseline (1600.985 us; speedup 1.0000x reference)
//
#include <hip/hip_runtime.h>
#include <hip/hip_bf16.h>
#include <math.h>

// Problem constants (fixed by the reference)
#define NN 50000
#define EE 400000
#define TT 4
#define DIN 64
#define DD 128
#define BB 64
#define STEPS 8
#define KAGG 544    // 512 (T*D) + 4 (per-type counts for b_msg) + 28 pad -> 17*32
#define KTOT 672    // 544 (g part) + 128 (h part) for the composed-gate GEMM
#define NGATES 512  // [r_sum, z_sum, i_n, h_n]
#define NBIN (4 * NN)             // (dst, etype) bins
#define NBLK ((NBIN + 255) / 256) // 782 scan blocks
#define MT64 ((NN + 63) / 64)     // 782 step blocks

typedef __attribute__((ext_vector_type(8))) short bf16x8;
typedef __attribute__((ext_vector_type(4))) float f32x4;
typedef __attribute__((address_space(3))) void lds_void;
typedef __attribute__((address_space(1))) void glob_void;

__device__ inline float bf2f(__hip_bfloat16 x) { return __bfloat162float(x); }

// ---------------------------------------------------------------- init (zero-pad 64->128)
// h kept ONLY in bf16 (hb); hini fp32 for residual+readout precision
__global__ void k_init_h(const float* __restrict__ feat, float* __restrict__ h1,
                         __hip_bfloat16* __restrict__ hb) {
    int idx = blockIdx.x * blockDim.x + threadIdx.x;
    if (idx >= NN * DD) return;
    int v = idx >> 7, d = idx & 127;
    float val = (d < DIN) ? feat[v * DIN + d] : 0.0f;
    h1[idx] = val;
    hb[idx] = __float2bfloat16(val);
}

__global__ void k_zero_i32(int* __restrict__ p, int n) {
    int idx = blockIdx.x * blockDim.x + threadIdx.x;
    if (idx < n) p[idx] = 0;
}
__global__ void k_zero_f32(float* __restrict__ p, int n) {
    int idx = blockIdx.x * blockDim.x + threadIdx.x;
    if (idx < n) p[idx] = 0.0f;
}

// ---------------------------------------------------------------- CSR build by (dst,type)
__global__ void k_hist(const int* __restrict__ dst, const int* __restrict__ etype,
                       int* __restrict__ deg2) {
    int e = blockIdx.x * blockDim.x + threadIdx.x;
    if (e < EE) atomicAdd(&deg2[dst[e] * 4 + etype[e]], 1);
}

// ---- 3-pass device-wide exclusive scan over deg2[NBIN] ----
__global__ __launch_bounds__(256) void k_scan_bsum(const int* __restrict__ deg2,
                                                   int* __restrict__ bsum) {
    __shared__ int red[256];
    int tid = threadIdx.x;
    int i = blockIdx.x * 256 + tid;
    int v = (i < NBIN) ? deg2[i] : 0;
    red[tid] = v;
    __syncthreads();
#pragma unroll
    for (int s = 128; s > 0; s >>= 1) {
        if (tid < s) red[tid] += red[tid + s];
        __syncthreads();
    }
    if (tid == 0) bsum[blockIdx.x] = red[0];
}

__global__ __launch_bounds__(1024) void k_scan_boff(const int* __restrict__ bsum,
                                                    int* __restrict__ boff) {
    __shared__ int s[1024];
    int tid = threadIdx.x;
    int v = (tid < NBLK) ? bsum[tid] : 0;
    s[tid] = v;
    __syncthreads();
    for (int d = 1; d < 1024; d <<= 1) {
        int t = (tid >= d) ? s[tid - d] : 0;
        __syncthreads();
        s[tid] += t;
        __syncthreads();
    }
    if (tid < NBLK) boff[tid] = s[tid] - v;  // exclusive
}

__global__ __launch_bounds__(256) void k_scan_final(const int* __restrict__ deg2,
                                                    const int* __restrict__ boff,
                                                    int* __restrict__ off2,
                                                    int* __restrict__ cursor) {
    __shared__ int s[256];
    int tid = threadIdx.x;
    int i = blockIdx.x * 256 + tid;
    int v = (i < NBIN) ? deg2[i] : 0;
    s[tid] = v;
    __syncthreads();
#pragma unroll
    for (int d = 1; d < 256; d <<= 1) {
        int t = (tid >= d) ? s[tid - d] : 0;
        __syncthreads();
        s[tid] += t;
        __syncthreads();
    }
    int excl = boff[blockIdx.x] + s[tid] - v;
    if (i < NBIN) {
        off2[i] = excl;
        cursor[i] = excl;
        if (i == NBIN - 1) off2[NBIN] = excl + v;  // == EE
    }
}

__global__ void k_fill(const int* __restrict__ dst, const int* __restrict__ src,
                       const int* __restrict__ etype, int* __restrict__ cursor,
                       int* __restrict__ csr_src) {
    int e = blockIdx.x * blockDim.x + threadIdx.x;
    if (e < EE) {
        int pos = atomicAdd(&cursor[dst[e] * 4 + etype[e]], 1);
        csr_src[pos] = src[e];
    }
}

// counts columns of g (cols 512..515) are constant across steps: write once.
// also zeroes the pad cols 516..543 (k_step reads them; W2 rows there are 0).
__global__ void k_counts(const int* __restrict__ off2, __hip_bfloat16* __restrict__ g) {
    int idx = blockIdx.x * blockDim.x + threadIdx.x;
    if (idx >= NN * 16) return;
    int v = idx >> 4, j = idx & 15;
    float x = 0.0f, y = 0.0f;
    if (j < 2) {
        int t0 = 2 * j;
        x = (float)(off2[4 * v + t0 + 1] - off2[4 * v + t0]);
        y = (float)(off2[4 * v + t0 + 2] - off2[4 * v + t0 + 1]);
    }
    __hip_bfloat162 o;
    o.x = __float2bfloat16(x);
    o.y = __float2bfloat16(y);
    ((__hip_bfloat162*)(g + (size_t)v * KAGG))[256 + j] = o;
}

// ---------------------------------------------------------------- weight prep (once/call)
// Composes W2[512 n][672 k] (bf16), k<544: (Wcat @ w_ih) for n<384 (0 for h_n cols),
// k>=544: w_hh arranged (0 for i_n cols). Also bias512.
// Gate cols n: 0..127 r_sum, 128..255 z_sum, 256..383 i_n, 384..511 h_n.
__global__ void k_prep2(const float* __restrict__ Wm, const float* __restrict__ bm,
                        const float* __restrict__ wih, const float* __restrict__ whh,
                        const float* __restrict__ bih, const float* __restrict__ bhh,
                        __hip_bfloat16* __restrict__ W2, float* __restrict__ bias512) {
    int idx = blockIdx.x * blockDim.x + threadIdx.x;
    if (idx < 512 * KTOT) {
        int n = idx / KTOT, k = idx % KTOT;
        float v = 0.0f;
        if (k < 544) {
            if (n < 384 && k < 516) {
                float s = 0.0f;
                if (k < 512) {
                    int t = k >> 7, d = k & 127;
                    const float* wr = Wm + (t << 14) + (d << 7);  // Wc[k][e] = Wm[t][d][e]
#pragma unroll 4
                    for (int e = 0; e < 128; ++e) s += wr[e] * wih[e * 384 + n];
                } else {
                    const float* br = bm + ((k - 512) << 7);
#pragma unroll 4
                    for (int e = 0; e < 128; ++e) s += br[e] * wih[e * 384 + n];
                }
                v = s;
            }
        } else {
            int dd = k - 544;
            if (n < 256) v = whh[dd * 384 + n];
            else if (n >= 384) v = whh[dd * 384 + n - 128];
        }
        W2[idx] = __float2bfloat16(v);
    } else {
        int b = idx - 512 * KTOT;
        if (b < NGATES) {
            float v;
            if (b < 256) v = bih[b] + bhh[b];
            else if (b < 384) v = bih[b];
            else v = bhh[b - 128];
            bias512[b] = v;
        }
    }
}

// ---------------------------------------------------------------- per-type aggregation
__global__ __launch_bounds__(256) void k_agg(const __hip_bfloat16* __restrict__ hb,
                                             const int* __restrict__ off2,
                                             const int* __restrict__ csr_src,
                                             __hip_bfloat16* __restrict__ g) {
    int node = (blockIdx.x * blockDim.x + threadIdx.x) >> 6;
    int lane = threadIdx.x & 63;
    if (node >= NN) return;
    const __hip_bfloat162* hb2 = (const __hip_bfloat162*)hb;
    __hip_bfloat162* grow = (__hip_bfloat162*)(g + (size_t)node * KAGG);
    int b0 = off2[4 * node];
    int b1 = off2[4 * node + 1];
    int b2 = off2[4 * node + 2];
    int b3 = off2[4 * node + 3];
    int b4 = off2[4 * node + 4];
    int beg[5] = {b0, b1, b2, b3, b4};
#pragma unroll
    for (int t = 0; t < TT; ++t) {
        float ax = 0.0f, ay = 0.0f;
        int p = beg[t], e = beg[t + 1];
        for (; p + 1 < e; p += 2) {
            int s0 = csr_src[p];
            int s1 = csr_src[p + 1];
            __hip_bfloat162 v0 = hb2[(size_t)s0 * 64 + lane];
            __hip_bfloat162 v1 = hb2[(size_t)s1 * 64 + lane];
            ax += bf2f(v0.x) + bf2f(v1.x);
            ay += bf2f(v0.y) + bf2f(v1.y);
        }
        if (p < e) {
            int s0 = csr_src[p];
            __hip_bfloat162 v0 = hb2[(size_t)s0 * 64 + lane];
            ax += bf2f(v0.x);
            ay += bf2f(v0.y);
        }
        __hip_bfloat162 o;
        o.x = __float2bfloat16(ax);
        o.y = __float2bfloat16(ay);
        grow[t * 64 + lane] = o;
    }
}

// ---------------------------------------------------------------- fused step kernel (64-row)
// Single composed GEMM: gates[64x512] = [g(544) | h(128)] @ W2^T, skipping zero blocks
// (i_n has no h-part, h_n has no g-part) via K-range per column tile.
// Wave w owns d-slice [32w,32w+32) of ALL FOUR gates -> GRU epilogue is wave-local.
// LDS tiles XOR-swizzled at 16B granularity (part ^= row&3), applied both-sides:
// pre-swizzled global source addr for global_load_lds + swizzled ds_read_b128.
__global__ __launch_bounds__(256) void k_step(const __hip_bfloat16* __restrict__ g,
                                              const __hip_bfloat16* __restrict__ W2,
                                              const float* __restrict__ bias512,
                                              const __hip_bfloat16* __restrict__ hbi,
                                              __hip_bfloat16* __restrict__ hbo) {
    __shared__ short As[64 * 32];   // 4 KB  A-chunk  (64 rows x 32 k)
    __shared__ short Bs[384 * 32];  // 24 KB B-chunk  (384 live gate-cols x 32 k)
    const int tid = threadIdx.x;
    const int lane = tid & 63;
    const int wave = tid >> 6;
    const int row0 = blockIdx.x * 64;
    const int quad = lane >> 4;
    const int m16 = lane & 15;
    const int koff = (quad * 8) ^ ((m16 & 3) << 3);  // swizzled k-offset (shorts)
    const int cb0 = 32 * wave;                        // this wave's d-slice base

    // A staging source (slot = tid): row arow, 16B part swizzled by row&3
    const int arow = tid >> 2;
    const int apart = (tid & 3) ^ (arow & 3);
    int agrow = row0 + arow;
    if (agrow >= NN) agrow = NN - 1;
    const __hip_bfloat16* gsrc = g + (size_t)agrow * KAGG + apart * 8;
    const __hip_bfloat16* hsrc = hbi + (size_t)agrow * DD + apart * 8;

    f32x4 acc[4][8];  // [row-tile][col-tile: r0,r1,z0,z1,in0,in1,hn0,hn1]
#pragma unroll
    for (int rt = 0; rt < 4; ++rt)
#pragma unroll
        for (int ct = 0; ct < 8; ++ct) acc[rt][ct] = (f32x4){0.f, 0.f, 0.f, 0.f};

    // ---------------- g-part: k = 0..543 (17 chunks) ----------------
    for (int ki = 0; ki < 17; ++ki) {
        const int k0 = ki * 32;
        __builtin_amdgcn_global_load_lds((const glob_void*)(gsrc + k0),
                                         (lds_void*)&As[(wave * 64) * 8], 16, 0, 0);
#pragma unroll
        for (int i = 0; i < 6; ++i) {  // B rows 0..383 (n = sr)
            int s = tid + i * 256;
            int sr = s >> 2;
            int bpart = (s & 3) ^ (sr & 3);
            __builtin_amdgcn_global_load_lds(
                (const glob_void*)(W2 + (size_t)sr * KTOT + k0 + bpart * 8),
                (lds_void*)&Bs[(wave * 64 + i * 256) * 8], 16, 0, 0);
        }
        __syncthreads();
        bf16x8 af[4];
#pragma unroll
        for (int rt = 0; rt < 4; ++rt)
            af[rt] = *(const bf16x8*)&As[(rt * 16 + m16) * 32 + koff];
#pragma unroll
        for (int c = 0; c < 6; ++c) {  // r0,r1,z0,z1,in0,in1
            const int lr = ((c >> 1) * 128) + ((c & 1) * 16) + cb0 + m16;
            bf16x8 bfr = *(const bf16x8*)&Bs[lr * 32 + koff];
#pragma unroll
            for (int rt = 0; rt < 4; ++rt)
                acc[rt][c] =
                    __builtin_amdgcn_mfma_f32_16x16x32_bf16(af[rt], bfr, acc[rt][c], 0, 0, 0);
        }
        __syncthreads();
    }

    // ---------------- h-part: k = 544..671 (4 chunks) ----------------
    for (int ki = 0; ki < 4; ++ki) {
        const int k0 = ki * 32;
        __builtin_amdgcn_global_load_lds((const glob_void*)(hsrc + k0),
                                         (lds_void*)&As[(wave * 64) * 8], 16, 0, 0);
#pragma unroll
        for (int i = 0; i < 6; ++i) {  // B rows: sr<256 -> n=sr (rz), sr>=256 -> n=sr+128 (h_n)
            int s = tid + i * 256;
            int sr = s >> 2;
            int n = (sr < 256) ? sr : sr + 128;
            int bpart = (s & 3) ^ (sr & 3);
            __builtin_amdgcn_global_load_lds(
                (const glob_void*)(W2 + (size_t)n * KTOT + 544 + k0 + bpart * 8),
                (lds_void*)&Bs[(wave * 64 + i * 256) * 8], 16, 0, 0);
        }
        __syncthreads();
        bf16x8 af[4];
#pragma unroll
        for (int rt = 0; rt < 4; ++rt)
            af[rt] = *(const bf16x8*)&As[(rt * 16 + m16) * 32 + koff];
#pragma unroll
        for (int c = 0; c < 6; ++c) {  // r0,r1,z0,z1,hn0,hn1 (hn lives at compacted rows 256+)
            const int lr = ((c >> 1) * 128) + ((c & 1) * 16) + cb0 + m16;
            const int ai = (c < 4) ? c : c + 2;  // acc col 0,1,2,3,6,7
            bf16x8 bfr = *(const bf16x8*)&Bs[lr * 32 + koff];
#pragma unroll
            for (int rt = 0; rt < 4; ++rt)
                acc[rt][ai] =
                    __builtin_amdgcn_mfma_f32_16x16x32_bf16(af[rt], bfr, acc[rt][ai], 0, 0, 0);
        }
        __syncthreads();
    }

    // ---------------- epilogue: in-register GRU (wave-local d-slice) ----------------
#pragma unroll
    for (int c = 0; c < 2; ++c) {
        const int d = cb0 + 16 * c + m16;
        const float brs = bias512[d];
        const float bzs = bias512[128 + d];
        const float bin_ = bias512[256 + d];
        const float bhn = bias512[384 + d];
#pragma unroll
        for (int rt = 0; rt < 4; ++rt) {
#pragma unroll
            for (int j = 0; j < 4; ++j) {
                const int rowl = rt * 16 + quad * 4 + j;
                const int grow = row0 + rowl;
                if (grow >= NN) continue;
                const float rs = acc[rt][c][j] + brs;
                const float zs = acc[rt][2 + c][j] + bzs;
                const float inn = acc[rt][4 + c][j] + bin_;
                const float hnn = acc[rt][6 + c][j] + bhn;
                const float rr = 1.0f / (1.0f + __expf(-rs));
                const float zz = 1.0f / (1.0f + __expf(-zs));
                const float ng = tanhf(inn + rr * hnn);
                const float hv = bf2f(hbi[(size_t)grow * DD + d]);
                const float o = (1.0f - zz) * ng + zz * hv;
                hbo[(size_t)grow * DD + d] = __float2bfloat16(o);
            }
        }
    }
}

// ---------------------------------------------------------------- readout (n2g is sorted)
__global__ __launch_bounds__(128) void k_readout(const __hip_bfloat16* __restrict__ h,
                                                 const float* __restrict__ h1,
                                                 const int* __restrict__ n2g,
                                                 float* __restrict__ feats) {
    const int CHN = 64;
    int d = threadIdx.x;
    int v0 = blockIdx.x * CHN;
    if (v0 >= NN) return;
    int v1 = v0 + CHN;
    if (v1 > NN) v1 = NN;
    float sum = 0.0f;
    int cur = n2g[v0];
    for (int v = v0; v < v1; ++v) {
        int gph = n2g[v];
        if (gph != cur) {
            atomicAdd(&feats[cur * DD + d], sum);
            sum = 0.0f;
            cur = gph;
        }
        sum += bf2f(h[(size_t)v * DD + d]) + h1[(size_t)v * DD + d];
    }
    atomicAdd(&feats[cur * DD + d], sum);
}

// ---------------------------------------------------------------- classifier
__global__ void k_cls(const float* __restrict__ feats, const float* __restrict__ Wc,
                      const float* __restrict__ bc, float* __restrict__ out) {
    int t = threadIdx.x;
    if (t >= BB * 2) return;
    int b = t >> 1, c = t & 1;
    float s = bc[c];
    for (int d = 0; d < DD; ++d) s += feats[b * DD + d] * Wc[d * 2 + c];
    out[t] = s;
}

// ================================================================ launcher
extern "C" void kernel_launch(void* const* d_in, const int* in_sizes, int n_in, void* d_out,
                              int out_size, void* d_ws, size_t ws_size, hipStream_t stream) {
    const float* features = (const float*)d_in[0];
    const int* src = (const int*)d_in[1];
    const int* dst = (const int*)d_in[2];
    const int* etype = (const int*)d_in[3];
    const int* n2g = (const int*)d_in[4];
    const float* W_msg = (const float*)d_in[5];
    const float* b_msg = (const float*)d_in[6];
    const float* w_ih = (const float*)d_in[7];
    const float* b_ih = (const float*)d_in[8];
    const float* w_hh = (const float*)d_in[9];
    const float* b_hh = (const float*)d_in[10];
    const float* W_cls = (const float*)d_in[11];
    const float* b_cls = (const float*)d_in[12];
    float* out = (float*)d_out;

    char* ws = (char*)d_ws;
    size_t o = 0;
    auto alloc = [&](size_t bytes) {
        o = (o + 255) & ~(size_t)255;
        void* p = ws + o;
        o += bytes;
        return p;
    };
    int* deg2 = (int*)alloc(sizeof(int) * NBIN);
    int* off2 = (int*)alloc(sizeof(int) * (NBIN + 1));
    int* cursor = (int*)alloc(sizeof(int) * NBIN);
    int* bsum = (int*)alloc(sizeof(int) * NBLK);
    int* boff = (int*)alloc(sizeof(int) * NBLK);
    int* csr_src = (int*)alloc(sizeof(int) * EE);
    __hip_bfloat16* W2 = (__hip_bfloat16*)alloc(sizeof(__hip_bfloat16) * 512 * KTOT);
    float* bias512 = (float*)alloc(sizeof(float) * NGATES);
    float* hini = (float*)alloc(sizeof(float) * (size_t)NN * DD);
    __hip_bfloat16* hbfA = (__hip_bfloat16*)alloc(sizeof(__hip_bfloat16) * (size_t)NN * DD);
    __hip_bfloat16* hbfB = (__hip_bfloat16*)alloc(sizeof(__hip_bfloat16) * (size_t)NN * DD);
    __hip_bfloat16* g = (__hip_bfloat16*)alloc(sizeof(__hip_bfloat16) * (size_t)NN * KAGG);
    float* feats = (float*)alloc(sizeof(float) * BB * DD);

    // setup
    k_init_h<<<(NN * DD + 255) / 256, 256, 0, stream>>>(features, hini, hbfA);
    k_zero_i32<<<(NBIN + 255) / 256, 256, 0, stream>>>(deg2, NBIN);
    k_zero_f32<<<(BB * DD + 255) / 256, 256, 0, stream>>>(feats, BB * DD);
    k_hist<<<(EE + 255) / 256, 256, 0, stream>>>(dst, etype, deg2);
    k_scan_bsum<<<NBLK, 256, 0, stream>>>(deg2, bsum);
    k_scan_boff<<<1, 1024, 0, stream>>>(bsum, boff);
    k_scan_final<<<NBLK, 256, 0, stream>>>(deg2, boff, off2, cursor);
    k_fill<<<(EE + 255) / 256, 256, 0, stream>>>(dst, src, etype, cursor, csr_src);
    k_counts<<<(NN * 16 + 255) / 256, 256, 0, stream>>>(off2, g);
    {
        int prep_n = 512 * KTOT + NGATES;
        k_prep2<<<(prep_n + 255) / 256, 256, 0, stream>>>(W_msg, b_msg, w_ih, w_hh, b_ih,
                                                          b_hh, W2, bias512);
    }

    __hip_bfloat16* hbc = hbfA;
    __hip_bfloat16* hbx = hbfB;
    for (int s = 0; s < STEPS; ++s) {
        k_agg<<<(NN * 64 + 255) / 256, 256, 0, stream>>>(hbc, off2, csr_src, g);
        k_step<<<MT64, 256, 0, stream>>>(g, W2, bias512, hbc, hbx);
        __hip_bfloat16* tb = hbc; hbc = hbx; hbx = tb;
    }
    k_readout<<<(NN + 63) / 64, 128, 0, stream>>>(hbc, hini, n2g, feats);
    k_cls<<<1, 128, 0, stream>>>(feats, W_cls, b_cls, out);
}

// Round 3
// 1219.487 us; speedup vs baseline: 1.3128x; 1.3128x over previous
//
#include <hip/hip_runtime.h>
#include <hip/hip_bf16.h>
#include <math.h>

// Problem constants (fixed by the reference)
#define NN 50000
#define EE 400000
#define TT 4
#define DIN 64
#define DD 128
#define BB 64
#define STEPS 8
#define KAGG 544    // 512 (T*D) + 4 (per-type counts for b_msg) + 28 pad -> 17*32
#define KTOT 672    // 544 (g part) + 128 (h part) for the composed-gate GEMM
#define NGATES 512  // [r_sum, z_sum, i_n, h_n]
#define NBIN (4 * NN)             // (dst, etype) bins
#define NBLK ((NBIN + 255) / 256) // 782 scan blocks
#define MT64 ((NN + 63) / 64)     // 782 step blocks

typedef __attribute__((ext_vector_type(8))) short bf16x8;
typedef __attribute__((ext_vector_type(4))) float f32x4;
typedef __attribute__((address_space(3))) void lds_void;
typedef __attribute__((address_space(1))) void glob_void;

__device__ inline float bf2f(__hip_bfloat16 x) { return __bfloat162float(x); }

// ---------------------------------------------------------------- init (zero-pad 64->128)
__global__ void k_init_h(const float* __restrict__ feat, float* __restrict__ h1,
                         __hip_bfloat16* __restrict__ hb) {
    int idx = blockIdx.x * blockDim.x + threadIdx.x;
    if (idx >= NN * DD) return;
    int v = idx >> 7, d = idx & 127;
    float val = (d < DIN) ? feat[v * DIN + d] : 0.0f;
    h1[idx] = val;
    hb[idx] = __float2bfloat16(val);
}

__global__ void k_zero_i32(int* __restrict__ p, int n) {
    int idx = blockIdx.x * blockDim.x + threadIdx.x;
    if (idx < n) p[idx] = 0;
}
__global__ void k_zero_f32(float* __restrict__ p, int n) {
    int idx = blockIdx.x * blockDim.x + threadIdx.x;
    if (idx < n) p[idx] = 0.0f;
}

// ---------------------------------------------------------------- CSR build by (dst,type)
__global__ void k_hist(const int* __restrict__ dst, const int* __restrict__ etype,
                       int* __restrict__ deg2) {
    int e = blockIdx.x * blockDim.x + threadIdx.x;
    if (e < EE) atomicAdd(&deg2[dst[e] * 4 + etype[e]], 1);
}

__global__ __launch_bounds__(256) void k_scan_bsum(const int* __restrict__ deg2,
                                                   int* __restrict__ bsum) {
    __shared__ int red[256];
    int tid = threadIdx.x;
    int i = blockIdx.x * 256 + tid;
    int v = (i < NBIN) ? deg2[i] : 0;
    red[tid] = v;
    __syncthreads();
#pragma unroll
    for (int s = 128; s > 0; s >>= 1) {
        if (tid < s) red[tid] += red[tid + s];
        __syncthreads();
    }
    if (tid == 0) bsum[blockIdx.x] = red[0];
}

__global__ __launch_bounds__(1024) void k_scan_boff(const int* __restrict__ bsum,
                                                    int* __restrict__ boff) {
    __shared__ int s[1024];
    int tid = threadIdx.x;
    int v = (tid < NBLK) ? bsum[tid] : 0;
    s[tid] = v;
    __syncthreads();
    for (int d = 1; d < 1024; d <<= 1) {
        int t = (tid >= d) ? s[tid - d] : 0;
        __syncthreads();
        s[tid] += t;
        __syncthreads();
    }
    if (tid < NBLK) boff[tid] = s[tid] - v;  // exclusive
}

__global__ __launch_bounds__(256) void k_scan_final(const int* __restrict__ deg2,
                                                    const int* __restrict__ boff,
                                                    int* __restrict__ off2,
                                                    int* __restrict__ cursor) {
    __shared__ int s[256];
    int tid = threadIdx.x;
    int i = blockIdx.x * 256 + tid;
    int v = (i < NBIN) ? deg2[i] : 0;
    s[tid] = v;
    __syncthreads();
#pragma unroll
    for (int d = 1; d < 256; d <<= 1) {
        int t = (tid >= d) ? s[tid - d] : 0;
        __syncthreads();
        s[tid] += t;
        __syncthreads();
    }
    int excl = boff[blockIdx.x] + s[tid] - v;
    if (i < NBIN) {
        off2[i] = excl;
        cursor[i] = excl;
        if (i == NBIN - 1) off2[NBIN] = excl + v;  // == EE
    }
}

__global__ void k_fill(const int* __restrict__ dst, const int* __restrict__ src,
                       const int* __restrict__ etype, int* __restrict__ cursor,
                       int* __restrict__ csr_src) {
    int e = blockIdx.x * blockDim.x + threadIdx.x;
    if (e < EE) {
        int pos = atomicAdd(&cursor[dst[e] * 4 + etype[e]], 1);
        csr_src[pos] = src[e];
    }
}

// counts columns of g (cols 512..515) constant across steps; zero pad 516..543.
__global__ void k_counts(const int* __restrict__ off2, __hip_bfloat16* __restrict__ g) {
    int idx = blockIdx.x * blockDim.x + threadIdx.x;
    if (idx >= NN * 16) return;
    int v = idx >> 4, j = idx & 15;
    float x = 0.0f, y = 0.0f;
    if (j < 2) {
        int t0 = 2 * j;
        x = (float)(off2[4 * v + t0 + 1] - off2[4 * v + t0]);
        y = (float)(off2[4 * v + t0 + 2] - off2[4 * v + t0 + 1]);
    }
    __hip_bfloat162 o;
    o.x = __float2bfloat16(x);
    o.y = __float2bfloat16(y);
    ((__hip_bfloat162*)(g + (size_t)v * KAGG))[256 + j] = o;
}

// ---------------------------------------------------------------- weight prep (once/call)
// W2[512 n][672 k] bf16: k<544 -> (Wcat @ w_ih) for n<384 (0 for h_n cols);
// k>=544 -> w_hh (0 for i_n cols). Gate cols n: 0..127 r, 128..255 z, 256..383 i_n, 384..511 h_n.
__global__ void k_prep2(const float* __restrict__ Wm, const float* __restrict__ bm,
                        const float* __restrict__ wih, const float* __restrict__ whh,
                        const float* __restrict__ bih, const float* __restrict__ bhh,
                        __hip_bfloat16* __restrict__ W2, float* __restrict__ bias512) {
    int idx = blockIdx.x * blockDim.x + threadIdx.x;
    if (idx < 512 * KTOT) {
        int n = idx / KTOT, k = idx % KTOT;
        float v = 0.0f;
        if (k < 544) {
            if (n < 384 && k < 516) {
                float s = 0.0f;
                if (k < 512) {
                    int t = k >> 7, d = k & 127;
                    const float* wr = Wm + (t << 14) + (d << 7);
#pragma unroll 4
                    for (int e = 0; e < 128; ++e) s += wr[e] * wih[e * 384 + n];
                } else {
                    const float* br = bm + ((k - 512) << 7);
#pragma unroll 4
                    for (int e = 0; e < 128; ++e) s += br[e] * wih[e * 384 + n];
                }
                v = s;
            }
        } else {
            int dd = k - 544;
            if (n < 256) v = whh[dd * 384 + n];
            else if (n >= 384) v = whh[dd * 384 + n - 128];
        }
        W2[idx] = __float2bfloat16(v);
    } else {
        int b = idx - 512 * KTOT;
        if (b < NGATES) {
            float v;
            if (b < 256) v = bih[b] + bhh[b];
            else if (b < 384) v = bih[b];
            else v = bhh[b - 128];
            bias512[b] = v;
        }
    }
}

// ---------------------------------------------------------------- per-type aggregation
__global__ __launch_bounds__(256) void k_agg(const __hip_bfloat16* __restrict__ hb,
                                             const int* __restrict__ off2,
                                             const int* __restrict__ csr_src,
                                             __hip_bfloat16* __restrict__ g) {
    int node = (blockIdx.x * blockDim.x + threadIdx.x) >> 6;
    int lane = threadIdx.x & 63;
    if (node >= NN) return;
    const __hip_bfloat162* hb2 = (const __hip_bfloat162*)hb;
    __hip_bfloat162* grow = (__hip_bfloat162*)(g + (size_t)node * KAGG);
    int b0 = off2[4 * node];
    int b1 = off2[4 * node + 1];
    int b2 = off2[4 * node + 2];
    int b3 = off2[4 * node + 3];
    int b4 = off2[4 * node + 4];
    int beg[5] = {b0, b1, b2, b3, b4};
#pragma unroll
    for (int t = 0; t < TT; ++t) {
        float ax = 0.0f, ay = 0.0f;
        int p = beg[t], e = beg[t + 1];
        for (; p + 1 < e; p += 2) {
            int s0 = csr_src[p];
            int s1 = csr_src[p + 1];
            __hip_bfloat162 v0 = hb2[(size_t)s0 * 64 + lane];
            __hip_bfloat162 v1 = hb2[(size_t)s1 * 64 + lane];
            ax += bf2f(v0.x) + bf2f(v1.x);
            ay += bf2f(v0.y) + bf2f(v1.y);
        }
        if (p < e) {
            int s0 = csr_src[p];
            __hip_bfloat162 v0 = hb2[(size_t)s0 * 64 + lane];
            ax += bf2f(v0.x);
            ay += bf2f(v0.y);
        }
        __hip_bfloat162 o;
        o.x = __float2bfloat16(ax);
        o.y = __float2bfloat16(ay);
        grow[t * 64 + lane] = o;
    }
}

// ---------------------------------------------------------------- fused step kernel
// gates[64x512] = [g(544)|h(128)] @ W2^T, composed weights, zero-blocks skipped.
// 2 N-passes (d 0..63, 64..127): acc[4][4]=64 VGPR -> 16 waves/CU.
// 2-phase double-buffered LDS pipeline: issue chunk k+1 loads, compute chunk k,
// single __syncthreads per chunk (drain sits after compute -> L2 latency hidden).
// Swizzle involution: 16B part ^= (row ^ (row>>2)) & 3  (2-way max bank aliasing).
__global__ __launch_bounds__(256, 4) void k_step(const __hip_bfloat16* __restrict__ g,
                                                 const __hip_bfloat16* __restrict__ W2,
                                                 const float* __restrict__ bias512,
                                                 const __hip_bfloat16* __restrict__ hbi,
                                                 __hip_bfloat16* __restrict__ hbo) {
    __shared__ __align__(16) short As[2][64 * 32];    // 2 x 4 KB
    __shared__ __align__(16) short Bs[2][192 * 32];   // 2 x 12 KB
    const int tid = threadIdx.x;
    const int lane = tid & 63;
    const int wave = tid >> 6;
    const int row0 = blockIdx.x * 64;
    const int quad = lane >> 4;
    const int m16 = lane & 15;
    // uniform read-side swizzled k-offset (shorts): slot = quad ^ f(row), f = (r^(r>>2))&3
    const int koff = ((quad ^ (m16 & 3) ^ ((m16 >> 2) & 3)) << 3);

    // A staging: slot tid -> row arow, 16B slot (tid&3) stores source part apart
    const int arow = tid >> 2;
    const int apart = (tid & 3) ^ ((arow ^ (arow >> 2)) & 3);
    int agrow = row0 + arow;
    if (agrow >= NN) agrow = NN - 1;
    const __hip_bfloat16* gA = g + (size_t)agrow * KAGG + apart * 8;
    const __hip_bfloat16* hA = hbi + (size_t)agrow * DD + apart * 8;

    for (int pass = 0; pass < 2; ++pass) {
        const int nb = 64 * pass;

        auto stage = [&](int ki, int buf) {
            // A chunk (4 KB): g-part for ki<17, h-part for ki>=17
            const glob_void* srcA =
                (ki < 17) ? (const glob_void*)(gA + ki * 32)
                          : (const glob_void*)(hA + (ki - 17) * 32);
            __builtin_amdgcn_global_load_lds(srcA, (lds_void*)&As[buf][(wave * 64) * 8],
                                             16, 0, 0);
            // B chunk (12 KB = 192 live gate rows x 32 k): groups r,z,(in|hn)
#pragma unroll
            for (int i = 0; i < 3; ++i) {
                int s = tid + i * 256;
                int br = s >> 2;
                int bpart = (s & 3) ^ ((br ^ (br >> 2)) & 3);
                int grp = br >> 6;       // 0:r 1:z 2:(in for g / hn for h)
                int within = br & 63;
                size_t n;
                int kk;
                if (ki < 17) {
                    n = (size_t)(grp * 128 + nb + within);
                    kk = ki * 32 + bpart * 8;
                } else {
                    n = (size_t)((grp < 2 ? grp * 128 : 384) + nb + within);
                    kk = 544 + (ki - 17) * 32 + bpart * 8;
                }
                __builtin_amdgcn_global_load_lds(
                    (const glob_void*)(W2 + n * KTOT + kk),
                    (lds_void*)&Bs[buf][(wave * 64 + i * 256) * 8], 16, 0, 0);
            }
        };

        f32x4 acc[4][4];
#pragma unroll
        for (int rt = 0; rt < 4; ++rt)
#pragma unroll
            for (int c = 0; c < 4; ++c) acc[rt][c] = (f32x4){0.f, 0.f, 0.f, 0.f};

        stage(0, 0);
        __syncthreads();

        for (int ki = 0; ki < 21; ++ki) {
            const int cur = ki & 1;
            if (ki + 1 < 21) stage(ki + 1, cur ^ 1);

            bf16x8 af[4];
#pragma unroll
            for (int rt = 0; rt < 4; ++rt)
                af[rt] = *(const bf16x8*)&As[cur][(rt * 16 + m16) * 32 + koff];
            const int brb = wave * 16 + m16;
            bf16x8 b0 = *(const bf16x8*)&Bs[cur][(brb) * 32 + koff];
            bf16x8 b1 = *(const bf16x8*)&Bs[cur][(64 + brb) * 32 + koff];
            bf16x8 b2 = *(const bf16x8*)&Bs[cur][(128 + brb) * 32 + koff];
#pragma unroll
            for (int rt = 0; rt < 4; ++rt)
                acc[rt][0] = __builtin_amdgcn_mfma_f32_16x16x32_bf16(af[rt], b0, acc[rt][0], 0, 0, 0);
#pragma unroll
            for (int rt = 0; rt < 4; ++rt)
                acc[rt][1] = __builtin_amdgcn_mfma_f32_16x16x32_bf16(af[rt], b1, acc[rt][1], 0, 0, 0);
            if (ki < 17) {
#pragma unroll
                for (int rt = 0; rt < 4; ++rt)
                    acc[rt][2] = __builtin_amdgcn_mfma_f32_16x16x32_bf16(af[rt], b2, acc[rt][2], 0, 0, 0);
            } else {
#pragma unroll
                for (int rt = 0; rt < 4; ++rt)
                    acc[rt][3] = __builtin_amdgcn_mfma_f32_16x16x32_bf16(af[rt], b2, acc[rt][3], 0, 0, 0);
            }
            __syncthreads();
        }

        // epilogue: in-register GRU for this pass's 16-wide d-slice per wave
        const int d = nb + wave * 16 + m16;
        const float brs = bias512[d];
        const float bzs = bias512[128 + d];
        const float bin_ = bias512[256 + d];
        const float bhn = bias512[384 + d];
#pragma unroll
        for (int rt = 0; rt < 4; ++rt) {
#pragma unroll
            for (int j = 0; j < 4; ++j) {
                const int rowl = rt * 16 + quad * 4 + j;
                const int grow = row0 + rowl;
                if (grow >= NN) continue;
                const float rs = acc[rt][0][j] + brs;
                const float zs = acc[rt][1][j] + bzs;
                const float inn = acc[rt][2][j] + bin_;
                const float hnn = acc[rt][3][j] + bhn;
                const float rr = 1.0f / (1.0f + __expf(-rs));
                const float zz = 1.0f / (1.0f + __expf(-zs));
                const float ng = tanhf(inn + rr * hnn);
                const float hv = bf2f(hbi[(size_t)grow * DD + d]);
                const float o = (1.0f - zz) * ng + zz * hv;
                hbo[(size_t)grow * DD + d] = __float2bfloat16(o);
            }
        }
    }
}

// ---------------------------------------------------------------- readout (n2g is sorted)
__global__ __launch_bounds__(128) void k_readout(const __hip_bfloat16* __restrict__ h,
                                                 const float* __restrict__ h1,
                                                 const int* __restrict__ n2g,
                                                 float* __restrict__ feats) {
    const int CHN = 64;
    int d = threadIdx.x;
    int v0 = blockIdx.x * CHN;
    if (v0 >= NN) return;
    int v1 = v0 + CHN;
    if (v1 > NN) v1 = NN;
    float sum = 0.0f;
    int cur = n2g[v0];
    for (int v = v0; v < v1; ++v) {
        int gph = n2g[v];
        if (gph != cur) {
            atomicAdd(&feats[cur * DD + d], sum);
            sum = 0.0f;
            cur = gph;
        }
        sum += bf2f(h[(size_t)v * DD + d]) + h1[(size_t)v * DD + d];
    }
    atomicAdd(&feats[cur * DD + d], sum);
}

// ---------------------------------------------------------------- classifier
__global__ void k_cls(const float* __restrict__ feats, const float* __restrict__ Wc,
                      const float* __restrict__ bc, float* __restrict__ out) {
    int t = threadIdx.x;
    if (t >= BB * 2) return;
    int b = t >> 1, c = t & 1;
    float s = bc[c];
    for (int d = 0; d < DD; ++d) s += feats[b * DD + d] * Wc[d * 2 + c];
    out[t] = s;
}

// ================================================================ launcher
extern "C" void kernel_launch(void* const* d_in, const int* in_sizes, int n_in, void* d_out,
                              int out_size, void* d_ws, size_t ws_size, hipStream_t stream) {
    const float* features = (const float*)d_in[0];
    const int* src = (const int*)d_in[1];
    const int* dst = (const int*)d_in[2];
    const int* etype = (const int*)d_in[3];
    const int* n2g = (const int*)d_in[4];
    const float* W_msg = (const float*)d_in[5];
    const float* b_msg = (const float*)d_in[6];
    const float* w_ih = (const float*)d_in[7];
    const float* b_ih = (const float*)d_in[8];
    const float* w_hh = (const float*)d_in[9];
    const float* b_hh = (const float*)d_in[10];
    const float* W_cls = (const float*)d_in[11];
    const float* b_cls = (const float*)d_in[12];
    float* out = (float*)d_out;

    char* ws = (char*)d_ws;
    size_t o = 0;
    auto alloc = [&](size_t bytes) {
        o = (o + 255) & ~(size_t)255;
        void* p = ws + o;
        o += bytes;
        return p;
    };
    int* deg2 = (int*)alloc(sizeof(int) * NBIN);
    int* off2 = (int*)alloc(sizeof(int) * (NBIN + 1));
    int* cursor = (int*)alloc(sizeof(int) * NBIN);
    int* bsum = (int*)alloc(sizeof(int) * NBLK);
    int* boff = (int*)alloc(sizeof(int) * NBLK);
    int* csr_src = (int*)alloc(sizeof(int) * EE);
    __hip_bfloat16* W2 = (__hip_bfloat16*)alloc(sizeof(__hip_bfloat16) * 512 * KTOT);
    float* bias512 = (float*)alloc(sizeof(float) * NGATES);
    float* hini = (float*)alloc(sizeof(float) * (size_t)NN * DD);
    __hip_bfloat16* hbfA = (__hip_bfloat16*)alloc(sizeof(__hip_bfloat16) * (size_t)NN * DD);
    __hip_bfloat16* hbfB = (__hip_bfloat16*)alloc(sizeof(__hip_bfloat16) * (size_t)NN * DD);
    __hip_bfloat16* g = (__hip_bfloat16*)alloc(sizeof(__hip_bfloat16) * (size_t)NN * KAGG);
    float* feats = (float*)alloc(sizeof(float) * BB * DD);

    // setup
    k_init_h<<<(NN * DD + 255) / 256, 256, 0, stream>>>(features, hini, hbfA);
    k_zero_i32<<<(NBIN + 255) / 256, 256, 0, stream>>>(deg2, NBIN);
    k_zero_f32<<<(BB * DD + 255) / 256, 256, 0, stream>>>(feats, BB * DD);
    k_hist<<<(EE + 255) / 256, 256, 0, stream>>>(dst, etype, deg2);
    k_scan_bsum<<<NBLK, 256, 0, stream>>>(deg2, bsum);
    k_scan_boff<<<1, 1024, 0, stream>>>(bsum, boff);
    k_scan_final<<<NBLK, 256, 0, stream>>>(deg2, boff, off2, cursor);
    k_fill<<<(EE + 255) / 256, 256, 0, stream>>>(dst, src, etype, cursor, csr_src);
    k_counts<<<(NN * 16 + 255) / 256, 256, 0, stream>>>(off2, g);
    {
        int prep_n = 512 * KTOT + NGATES;
        k_prep2<<<(prep_n + 255) / 256, 256, 0, stream>>>(W_msg, b_msg, w_ih, w_hh, b_ih,
                                                          b_hh, W2, bias512);
    }

    __hip_bfloat16* hbc = hbfA;
    __hip_bfloat16* hbx = hbfB;
    for (int s = 0; s < STEPS; ++s) {
        k_agg<<<(NN * 64 + 255) / 256, 256, 0, stream>>>(hbc, off2, csr_src, g);
        k_step<<<MT64, 256, 0, stream>>>(g, W2, bias512, hbc, hbx);
        __hip_bfloat16* tb = hbc; hbc = hbx; hbx = tb;
    }
    k_readout<<<(NN + 63) / 64, 128, 0, stream>>>(hbc, hini, n2g, feats);
    k_cls<<<1, 128, 0, stream>>>(feats, W_cls, b_cls, out);
}

// Round 4
// 965.989 us; speedup vs baseline: 1.6574x; 1.2624x over previous
//
#include <hip/hip_runtime.h>
#include <hip/hip_bf16.h>
#include <math.h>

// Problem constants (fixed by the reference)
#define NN 50000
#define EE 400000
#define TT 4
#define DIN 64
#define DD 128
#define BB 64
#define STEPS 8
#define KAGG 544    // 512 (T*D) + 4 (per-type counts for b_msg) + 28 pad -> 17*32
#define KTOT 672    // 544 (g part) + 128 (h part) for the composed-gate GEMM
#define NGATES 512  // [r_sum, z_sum, i_n, h_n]
#define NBIN (4 * NN)             // (dst, etype) bins
#define NBLK ((NBIN + 255) / 256) // 782 scan blocks
#define MT64 ((NN + 63) / 64)     // 782 step blocks

typedef __attribute__((ext_vector_type(8))) short bf16x8;
typedef __attribute__((ext_vector_type(4))) float f32x4;
typedef __attribute__((address_space(3))) void lds_void;
typedef __attribute__((address_space(1))) void glob_void;

__device__ inline float bf2f(__hip_bfloat16 x) { return __bfloat162float(x); }

// ---------------------------------------------------------------- init (zero-pad 64->128)
__global__ void k_init_h(const float* __restrict__ feat, float* __restrict__ h1,
                         __hip_bfloat16* __restrict__ hb) {
    int idx = blockIdx.x * blockDim.x + threadIdx.x;
    if (idx >= NN * DD) return;
    int v = idx >> 7, d = idx & 127;
    float val = (d < DIN) ? feat[v * DIN + d] : 0.0f;
    h1[idx] = val;
    hb[idx] = __float2bfloat16(val);
}

__global__ void k_zero_i32(int* __restrict__ p, int n) {
    int idx = blockIdx.x * blockDim.x + threadIdx.x;
    if (idx < n) p[idx] = 0;
}
__global__ void k_zero_f32(float* __restrict__ p, int n) {
    int idx = blockIdx.x * blockDim.x + threadIdx.x;
    if (idx < n) p[idx] = 0.0f;
}

// ---------------------------------------------------------------- CSR build by (dst,type)
__global__ void k_hist(const int* __restrict__ dst, const int* __restrict__ etype,
                       int* __restrict__ deg2) {
    int e = blockIdx.x * blockDim.x + threadIdx.x;
    if (e < EE) atomicAdd(&deg2[dst[e] * 4 + etype[e]], 1);
}

__global__ __launch_bounds__(256) void k_scan_bsum(const int* __restrict__ deg2,
                                                   int* __restrict__ bsum) {
    __shared__ int red[256];
    int tid = threadIdx.x;
    int i = blockIdx.x * 256 + tid;
    int v = (i < NBIN) ? deg2[i] : 0;
    red[tid] = v;
    __syncthreads();
#pragma unroll
    for (int s = 128; s > 0; s >>= 1) {
        if (tid < s) red[tid] += red[tid + s];
        __syncthreads();
    }
    if (tid == 0) bsum[blockIdx.x] = red[0];
}

__global__ __launch_bounds__(1024) void k_scan_boff(const int* __restrict__ bsum,
                                                    int* __restrict__ boff) {
    __shared__ int s[1024];
    int tid = threadIdx.x;
    int v = (tid < NBLK) ? bsum[tid] : 0;
    s[tid] = v;
    __syncthreads();
    for (int d = 1; d < 1024; d <<= 1) {
        int t = (tid >= d) ? s[tid - d] : 0;
        __syncthreads();
        s[tid] += t;
        __syncthreads();
    }
    if (tid < NBLK) boff[tid] = s[tid] - v;  // exclusive
}

__global__ __launch_bounds__(256) void k_scan_final(const int* __restrict__ deg2,
                                                    const int* __restrict__ boff,
                                                    int* __restrict__ off2,
                                                    int* __restrict__ cursor) {
    __shared__ int s[256];
    int tid = threadIdx.x;
    int i = blockIdx.x * 256 + tid;
    int v = (i < NBIN) ? deg2[i] : 0;
    s[tid] = v;
    __syncthreads();
#pragma unroll
    for (int d = 1; d < 256; d <<= 1) {
        int t = (tid >= d) ? s[tid - d] : 0;
        __syncthreads();
        s[tid] += t;
        __syncthreads();
    }
    int excl = boff[blockIdx.x] + s[tid] - v;
    if (i < NBIN) {
        off2[i] = excl;
        cursor[i] = excl;
        if (i == NBIN - 1) off2[NBIN] = excl + v;  // == EE
    }
}

__global__ void k_fill(const int* __restrict__ dst, const int* __restrict__ src,
                       const int* __restrict__ etype, int* __restrict__ cursor,
                       int* __restrict__ csr_src) {
    int e = blockIdx.x * blockDim.x + threadIdx.x;
    if (e < EE) {
        int pos = atomicAdd(&cursor[dst[e] * 4 + etype[e]], 1);
        csr_src[pos] = src[e];
    }
}

// counts columns of g (cols 512..515) constant across steps; zero pad 516..543.
__global__ void k_counts(const int* __restrict__ off2, __hip_bfloat16* __restrict__ g) {
    int idx = blockIdx.x * blockDim.x + threadIdx.x;
    if (idx >= NN * 16) return;
    int v = idx >> 4, j = idx & 15;
    float x = 0.0f, y = 0.0f;
    if (j < 2) {
        int t0 = 2 * j;
        x = (float)(off2[4 * v + t0 + 1] - off2[4 * v + t0]);
        y = (float)(off2[4 * v + t0 + 2] - off2[4 * v + t0 + 1]);
    }
    __hip_bfloat162 o;
    o.x = __float2bfloat16(x);
    o.y = __float2bfloat16(y);
    ((__hip_bfloat162*)(g + (size_t)v * KAGG))[256 + j] = o;
}

// ---------------------------------------------------------------- weight prep (once/call)
// W2[512 n][672 k] bf16: k<544 -> (Wcat @ w_ih) for n<384 (0 for h_n cols);
// k>=544 -> w_hh (0 for i_n cols). Gate cols n: 0..127 r, 128..255 z, 256..383 i_n, 384..511 h_n.
__global__ void k_prep2(const float* __restrict__ Wm, const float* __restrict__ bm,
                        const float* __restrict__ wih, const float* __restrict__ whh,
                        const float* __restrict__ bih, const float* __restrict__ bhh,
                        __hip_bfloat16* __restrict__ W2, float* __restrict__ bias512) {
    int idx = blockIdx.x * blockDim.x + threadIdx.x;
    if (idx < 512 * KTOT) {
        int n = idx / KTOT, k = idx % KTOT;
        float v = 0.0f;
        if (k < 544) {
            if (n < 384 && k < 516) {
                float s = 0.0f;
                if (k < 512) {
                    int t = k >> 7, d = k & 127;
                    const float* wr = Wm + (t << 14) + (d << 7);
#pragma unroll 4
                    for (int e = 0; e < 128; ++e) s += wr[e] * wih[e * 384 + n];
                } else {
                    const float* br = bm + ((k - 512) << 7);
#pragma unroll 4
                    for (int e = 0; e < 128; ++e) s += br[e] * wih[e * 384 + n];
                }
                v = s;
            }
        } else {
            int dd = k - 544;
            if (n < 256) v = whh[dd * 384 + n];
            else if (n >= 384) v = whh[dd * 384 + n - 128];
        }
        W2[idx] = __float2bfloat16(v);
    } else {
        int b = idx - 512 * KTOT;
        if (b < NGATES) {
            float v;
            if (b < 256) v = bih[b] + bhh[b];
            else if (b < 384) v = bih[b];
            else v = bhh[b - 128];
            bias512[b] = v;
        }
    }
}

// ---------------------------------------------------------------- per-type aggregation
__global__ __launch_bounds__(256) void k_agg(const __hip_bfloat16* __restrict__ hb,
                                             const int* __restrict__ off2,
                                             const int* __restrict__ csr_src,
                                             __hip_bfloat16* __restrict__ g) {
    int node = (blockIdx.x * blockDim.x + threadIdx.x) >> 6;
    int lane = threadIdx.x & 63;
    if (node >= NN) return;
    const __hip_bfloat162* hb2 = (const __hip_bfloat162*)hb;
    __hip_bfloat162* grow = (__hip_bfloat162*)(g + (size_t)node * KAGG);
    int b0 = off2[4 * node];
    int b1 = off2[4 * node + 1];
    int b2 = off2[4 * node + 2];
    int b3 = off2[4 * node + 3];
    int b4 = off2[4 * node + 4];
    int beg[5] = {b0, b1, b2, b3, b4};
#pragma unroll
    for (int t = 0; t < TT; ++t) {
        float ax = 0.0f, ay = 0.0f;
        int p = beg[t], e = beg[t + 1];
        for (; p + 1 < e; p += 2) {
            int s0 = csr_src[p];
            int s1 = csr_src[p + 1];
            __hip_bfloat162 v0 = hb2[(size_t)s0 * 64 + lane];
            __hip_bfloat162 v1 = hb2[(size_t)s1 * 64 + lane];
            ax += bf2f(v0.x) + bf2f(v1.x);
            ay += bf2f(v0.y) + bf2f(v1.y);
        }
        if (p < e) {
            int s0 = csr_src[p];
            __hip_bfloat162 v0 = hb2[(size_t)s0 * 64 + lane];
            ax += bf2f(v0.x);
            ay += bf2f(v0.y);
        }
        __hip_bfloat162 o;
        o.x = __float2bfloat16(ax);
        o.y = __float2bfloat16(ay);
        grow[t * 64 + lane] = o;
    }
}

// ---------------------------------------------------------------- fused step kernel (v3)
// gates[64x512] = [g(544)|h(128)] @ W2^T, composed weights, zero-blocks skipped.
// SINGLE pass over g (the round-3 2-pass doubled g traffic): 512 threads / 8 waves,
// each wave owns a 16-wide d-slice of ALL FOUR gates -> acc[4][4] = 64 VGPR.
// 2-deep double-buffered LDS pipeline, one __syncthreads per 32-k chunk.
// Output staged through LDS and written as full 256B rows (round-3 partial-line
// writes caused 5x WRITE amplification).
__global__ __launch_bounds__(512, 4) void k_step(const __hip_bfloat16* __restrict__ g,
                                                 const __hip_bfloat16* __restrict__ W2,
                                                 const float* __restrict__ bias512,
                                                 const __hip_bfloat16* __restrict__ hbi,
                                                 __hip_bfloat16* __restrict__ hbo) {
    __shared__ __align__(16) short As[2][64 * 32];    // 2 x 4 KB
    __shared__ __align__(16) short Bs[2][384 * 32];   // 2 x 24 KB
    const int tid = threadIdx.x;
    const int lane = tid & 63;
    const int wave = tid >> 6;
    const int row0 = blockIdx.x * 64;
    const int quad = lane >> 4;
    const int m16 = lane & 15;
    // read-side swizzled k-offset (shorts): slot = quad ^ f(row), f(r) = (r ^ (r>>2)) & 3
    const int koff = ((quad ^ ((m16 ^ (m16 >> 2)) & 3)) << 3);

    // A staging mapping (waves 0..3 only; slot = tid < 256): row = slot>>2,
    // LDS 16B slot (slot&3) sourced from global part (slot&3) ^ f(row)
    const int arow = tid >> 2;
    const int apart = (tid & 3) ^ ((arow ^ (arow >> 2)) & 3);
    int agrow = row0 + arow;
    if (agrow >= NN) agrow = NN - 1;
    const __hip_bfloat16* gA = g + (size_t)agrow * KAGG + apart * 8;
    const __hip_bfloat16* hA = hbi + (size_t)agrow * DD + apart * 8;

    auto stage = [&](int ki, int buf) {
        if (wave < 4) {  // A chunk: 64 rows x 32 k = 256 slots
            const glob_void* srcA = (ki < 17)
                                        ? (const glob_void*)(gA + ki * 32)
                                        : (const glob_void*)(hA + (ki - 17) * 32);
            __builtin_amdgcn_global_load_lds(srcA, (lds_void*)&As[buf][(wave * 64) * 8],
                                             16, 0, 0);
        }
        // B chunk: 384 live gate rows x 32 k = 1536 slots (3 per thread)
#pragma unroll
        for (int i = 0; i < 3; ++i) {
            int s = tid + i * 512;
            int br = s >> 2;
            int bpart = (s & 3) ^ ((br ^ (br >> 2)) & 3);
            int grp = br >> 7;        // 0:r  1:z  2:(i_n for g-chunks / h_n for h-chunks)
            int within = br & 127;
            size_t n;
            int kk;
            if (ki < 17) {
                n = (size_t)(grp * 128 + within);
                kk = ki * 32 + bpart * 8;
            } else {
                n = (size_t)((grp < 2 ? grp * 128 : 384) + within);
                kk = 544 + (ki - 17) * 32 + bpart * 8;
            }
            __builtin_amdgcn_global_load_lds((const glob_void*)(W2 + n * KTOT + kk),
                                             (lds_void*)&Bs[buf][(wave * 64 + i * 512) * 8],
                                             16, 0, 0);
        }
    };

    f32x4 acc[4][4];  // [row-tile][gate: r,z,in,hn]
#pragma unroll
    for (int rt = 0; rt < 4; ++rt)
#pragma unroll
        for (int c = 0; c < 4; ++c) acc[rt][c] = (f32x4){0.f, 0.f, 0.f, 0.f};

    stage(0, 0);
    __syncthreads();

    for (int ki = 0; ki < 21; ++ki) {
        const int cur = ki & 1;
        if (ki + 1 < 21) stage(ki + 1, cur ^ 1);

        bf16x8 af[4];
#pragma unroll
        for (int rt = 0; rt < 4; ++rt)
            af[rt] = *(const bf16x8*)&As[cur][(rt * 16 + m16) * 32 + koff];
        const int brb = wave * 16 + m16;
        bf16x8 b0 = *(const bf16x8*)&Bs[cur][(brb) * 32 + koff];
        bf16x8 b1 = *(const bf16x8*)&Bs[cur][(128 + brb) * 32 + koff];
        bf16x8 b2 = *(const bf16x8*)&Bs[cur][(256 + brb) * 32 + koff];
#pragma unroll
        for (int rt = 0; rt < 4; ++rt)
            acc[rt][0] = __builtin_amdgcn_mfma_f32_16x16x32_bf16(af[rt], b0, acc[rt][0], 0, 0, 0);
#pragma unroll
        for (int rt = 0; rt < 4; ++rt)
            acc[rt][1] = __builtin_amdgcn_mfma_f32_16x16x32_bf16(af[rt], b1, acc[rt][1], 0, 0, 0);
        if (ki < 17) {
#pragma unroll
            for (int rt = 0; rt < 4; ++rt)
                acc[rt][2] = __builtin_amdgcn_mfma_f32_16x16x32_bf16(af[rt], b2, acc[rt][2], 0, 0, 0);
        } else {
#pragma unroll
            for (int rt = 0; rt < 4; ++rt)
                acc[rt][3] = __builtin_amdgcn_mfma_f32_16x16x32_bf16(af[rt], b2, acc[rt][3], 0, 0, 0);
        }
        __syncthreads();
    }

    // ---------------- epilogue: in-register GRU -> LDS -> full-line global write ----
    short* Ht = &Bs[0][0];  // 64x128 bf16 = 16 KB (Bs[0] is free after last barrier)
    {
        const int d = wave * 16 + m16;
        const float brs = bias512[d];
        const float bzs = bias512[128 + d];
        const float bin_ = bias512[256 + d];
        const float bhn = bias512[384 + d];
#pragma unroll
        for (int rt = 0; rt < 4; ++rt) {
#pragma unroll
            for (int j = 0; j < 4; ++j) {
                const int rowl = rt * 16 + quad * 4 + j;
                const int grow = row0 + rowl;
                const float rs = acc[rt][0][j] + brs;
                const float zs = acc[rt][1][j] + bzs;
                const float inn = acc[rt][2][j] + bin_;
                const float hnn = acc[rt][3][j] + bhn;
                const float rr = 1.0f / (1.0f + __expf(-rs));
                const float zz = 1.0f / (1.0f + __expf(-zs));
                const float ng = tanhf(inn + rr * hnn);
                const float hv =
                    bf2f(hbi[(size_t)(grow < NN ? grow : NN - 1) * DD + d]);
                const float o = (1.0f - zz) * ng + zz * hv;
                __hip_bfloat16 ob = __float2bfloat16(o);
                Ht[rowl * 128 + d] = *(short*)&ob;
            }
        }
    }
    __syncthreads();
    {
        // 512 threads x 32 B contiguous -> fully-coalesced full-line stores
        const int row = tid >> 3;
        const int col = (tid & 7) * 16;
        if (row0 + row < NN) {
            bf16x8 v0 = *(const bf16x8*)&Ht[row * 128 + col];
            bf16x8 v1 = *(const bf16x8*)&Ht[row * 128 + col + 8];
            __hip_bfloat16* dstp = hbo + (size_t)(row0 + row) * DD + col;
            *(bf16x8*)dstp = v0;
            *(bf16x8*)(dstp + 8) = v1;
        }
    }
}

// ---------------------------------------------------------------- readout (n2g is sorted)
__global__ __launch_bounds__(128) void k_readout(const __hip_bfloat16* __restrict__ h,
                                                 const float* __restrict__ h1,
                                                 const int* __restrict__ n2g,
                                                 float* __restrict__ feats) {
    const int CHN = 64;
    int d = threadIdx.x;
    int v0 = blockIdx.x * CHN;
    if (v0 >= NN) return;
    int v1 = v0 + CHN;
    if (v1 > NN) v1 = NN;
    float sum = 0.0f;
    int cur = n2g[v0];
    for (int v = v0; v < v1; ++v) {
        int gph = n2g[v];
        if (gph != cur) {
            atomicAdd(&feats[cur * DD + d], sum);
            sum = 0.0f;
            cur = gph;
        }
        sum += bf2f(h[(size_t)v * DD + d]) + h1[(size_t)v * DD + d];
    }
    atomicAdd(&feats[cur * DD + d], sum);
}

// ---------------------------------------------------------------- classifier
__global__ void k_cls(const float* __restrict__ feats, const float* __restrict__ Wc,
                      const float* __restrict__ bc, float* __restrict__ out) {
    int t = threadIdx.x;
    if (t >= BB * 2) return;
    int b = t >> 1, c = t & 1;
    float s = bc[c];
    for (int d = 0; d < DD; ++d) s += feats[b * DD + d] * Wc[d * 2 + c];
    out[t] = s;
}

// ================================================================ launcher
extern "C" void kernel_launch(void* const* d_in, const int* in_sizes, int n_in, void* d_out,
                              int out_size, void* d_ws, size_t ws_size, hipStream_t stream) {
    const float* features = (const float*)d_in[0];
    const int* src = (const int*)d_in[1];
    const int* dst = (const int*)d_in[2];
    const int* etype = (const int*)d_in[3];
    const int* n2g = (const int*)d_in[4];
    const float* W_msg = (const float*)d_in[5];
    const float* b_msg = (const float*)d_in[6];
    const float* w_ih = (const float*)d_in[7];
    const float* b_ih = (const float*)d_in[8];
    const float* w_hh = (const float*)d_in[9];
    const float* b_hh = (const float*)d_in[10];
    const float* W_cls = (const float*)d_in[11];
    const float* b_cls = (const float*)d_in[12];
    float* out = (float*)d_out;

    char* ws = (char*)d_ws;
    size_t o = 0;
    auto alloc = [&](size_t bytes) {
        o = (o + 255) & ~(size_t)255;
        void* p = ws + o;
        o += bytes;
        return p;
    };
    int* deg2 = (int*)alloc(sizeof(int) * NBIN);
    int* off2 = (int*)alloc(sizeof(int) * (NBIN + 1));
    int* cursor = (int*)alloc(sizeof(int) * NBIN);
    int* bsum = (int*)alloc(sizeof(int) * NBLK);
    int* boff = (int*)alloc(sizeof(int) * NBLK);
    int* csr_src = (int*)alloc(sizeof(int) * EE);
    __hip_bfloat16* W2 = (__hip_bfloat16*)alloc(sizeof(__hip_bfloat16) * 512 * KTOT);
    float* bias512 = (float*)alloc(sizeof(float) * NGATES);
    float* hini = (float*)alloc(sizeof(float) * (size_t)NN * DD);
    __hip_bfloat16* hbfA = (__hip_bfloat16*)alloc(sizeof(__hip_bfloat16) * (size_t)NN * DD);
    __hip_bfloat16* hbfB = (__hip_bfloat16*)alloc(sizeof(__hip_bfloat16) * (size_t)NN * DD);
    __hip_bfloat16* g = (__hip_bfloat16*)alloc(sizeof(__hip_bfloat16) * (size_t)NN * KAGG);
    float* feats = (float*)alloc(sizeof(float) * BB * DD);

    // setup
    k_init_h<<<(NN * DD + 255) / 256, 256, 0, stream>>>(features, hini, hbfA);
    k_zero_i32<<<(NBIN + 255) / 256, 256, 0, stream>>>(deg2, NBIN);
    k_zero_f32<<<(BB * DD + 255) / 256, 256, 0, stream>>>(feats, BB * DD);
    k_hist<<<(EE + 255) / 256, 256, 0, stream>>>(dst, etype, deg2);
    k_scan_bsum<<<NBLK, 256, 0, stream>>>(deg2, bsum);
    k_scan_boff<<<1, 1024, 0, stream>>>(bsum, boff);
    k_scan_final<<<NBLK, 256, 0, stream>>>(deg2, boff, off2, cursor);
    k_fill<<<(EE + 255) / 256, 256, 0, stream>>>(dst, src, etype, cursor, csr_src);
    k_counts<<<(NN * 16 + 255) / 256, 256, 0, stream>>>(off2, g);
    {
        int prep_n = 512 * KTOT + NGATES;
        k_prep2<<<(prep_n + 255) / 256, 256, 0, stream>>>(W_msg, b_msg, w_ih, w_hh, b_ih,
                                                          b_hh, W2, bias512);
    }

    __hip_bfloat16* hbc = hbfA;
    __hip_bfloat16* hbx = hbfB;
    for (int s = 0; s < STEPS; ++s) {
        k_agg<<<(NN * 64 + 255) / 256, 256, 0, stream>>>(hbc, off2, csr_src, g);
        k_step<<<MT64, 512, 0, stream>>>(g, W2, bias512, hbc, hbx);
        __hip_bfloat16* tb = hbc; hbc = hbx; hbx = tb;
    }
    k_readout<<<(NN + 63) / 64, 128, 0, stream>>>(hbc, hini, n2g, feats);
    k_cls<<<1, 128, 0, stream>>>(feats, W_cls, b_cls, out);
}

// Round 6
// 957.755 us; speedup vs baseline: 1.6716x; 1.0086x over previous
//
#include <hip/hip_runtime.h>
#include <hip/hip_bf16.h>
#include <math.h>

// Problem constants (fixed by the reference)
#define NN 50000
#define EE 400000
#define TT 4
#define DIN 64
#define DD 128
#define BB 64
#define STEPS 8
#define KAGG 544    // 512 (T*D) + 4 (per-type counts for b_msg) + 28 pad -> 17*32
#define KTOT 672    // 544 (g part) + 128 (h part) for the composed-gate GEMM
#define NGATES 512  // [r_sum, z_sum, i_n, h_n]
#define NBIN (4 * NN)             // (dst, etype) bins
#define NBLK ((NBIN + 255) / 256) // 782 scan blocks
#define MT64 ((NN + 63) / 64)     // 782 step blocks

typedef __attribute__((ext_vector_type(8))) short bf16x8;
typedef __attribute__((ext_vector_type(4))) float f32x4;
typedef __attribute__((address_space(3))) void lds_void;
typedef __attribute__((address_space(1))) void glob_void;

__device__ inline float bf2f(__hip_bfloat16 x) { return __bfloat162float(x); }

// ---------------------------------------------------------------- init (zero-pad 64->128)
__global__ void k_init_h(const float* __restrict__ feat, float* __restrict__ h1,
                         __hip_bfloat16* __restrict__ hb) {
    int idx = blockIdx.x * blockDim.x + threadIdx.x;
    if (idx >= NN * DD) return;
    int v = idx >> 7, d = idx & 127;
    float val = (d < DIN) ? feat[v * DIN + d] : 0.0f;
    h1[idx] = val;
    hb[idx] = __float2bfloat16(val);
}

__global__ void k_zero_i32(int* __restrict__ p, int n) {
    int idx = blockIdx.x * blockDim.x + threadIdx.x;
    if (idx < n) p[idx] = 0;
}
__global__ void k_zero_f32(float* __restrict__ p, int n) {
    int idx = blockIdx.x * blockDim.x + threadIdx.x;
    if (idx < n) p[idx] = 0.0f;
}

// ---------------------------------------------------------------- CSR build by (dst,type)
__global__ void k_hist(const int* __restrict__ dst, const int* __restrict__ etype,
                       int* __restrict__ deg2) {
    int e = blockIdx.x * blockDim.x + threadIdx.x;
    if (e < EE) atomicAdd(&deg2[dst[e] * 4 + etype[e]], 1);
}

__global__ __launch_bounds__(256) void k_scan_bsum(const int* __restrict__ deg2,
                                                   int* __restrict__ bsum) {
    __shared__ int red[256];
    int tid = threadIdx.x;
    int i = blockIdx.x * 256 + tid;
    int v = (i < NBIN) ? deg2[i] : 0;
    red[tid] = v;
    __syncthreads();
#pragma unroll
    for (int s = 128; s > 0; s >>= 1) {
        if (tid < s) red[tid] += red[tid + s];
        __syncthreads();
    }
    if (tid == 0) bsum[blockIdx.x] = red[0];
}

__global__ __launch_bounds__(1024) void k_scan_boff(const int* __restrict__ bsum,
                                                    int* __restrict__ boff) {
    __shared__ int s[1024];
    int tid = threadIdx.x;
    int v = (tid < NBLK) ? bsum[tid] : 0;
    s[tid] = v;
    __syncthreads();
    for (int d = 1; d < 1024; d <<= 1) {
        int t = (tid >= d) ? s[tid - d] : 0;
        __syncthreads();
        s[tid] += t;
        __syncthreads();
    }
    if (tid < NBLK) boff[tid] = s[tid] - v;  // exclusive
}

__global__ __launch_bounds__(256) void k_scan_final(const int* __restrict__ deg2,
                                                    const int* __restrict__ boff,
                                                    int* __restrict__ off2,
                                                    int* __restrict__ cursor) {
    __shared__ int s[256];
    int tid = threadIdx.x;
    int i = blockIdx.x * 256 + tid;
    int v = (i < NBIN) ? deg2[i] : 0;
    s[tid] = v;
    __syncthreads();
#pragma unroll
    for (int d = 1; d < 256; d <<= 1) {
        int t = (tid >= d) ? s[tid - d] : 0;
        __syncthreads();
        s[tid] += t;
        __syncthreads();
    }
    int excl = boff[blockIdx.x] + s[tid] - v;
    if (i < NBIN) {
        off2[i] = excl;
        cursor[i] = excl;
        if (i == NBIN - 1) off2[NBIN] = excl + v;  // == EE
    }
}

__global__ void k_fill(const int* __restrict__ dst, const int* __restrict__ src,
                       const int* __restrict__ etype, int* __restrict__ cursor,
                       int* __restrict__ csr_src) {
    int e = blockIdx.x * blockDim.x + threadIdx.x;
    if (e < EE) {
        int pos = atomicAdd(&cursor[dst[e] * 4 + etype[e]], 1);
        csr_src[pos] = src[e];
    }
}

// counts columns of g (cols 512..515) constant across steps; zero pad 516..543.
__global__ void k_counts(const int* __restrict__ off2, __hip_bfloat16* __restrict__ g) {
    int idx = blockIdx.x * blockDim.x + threadIdx.x;
    if (idx >= NN * 16) return;
    int v = idx >> 4, j = idx & 15;
    float x = 0.0f, y = 0.0f;
    if (j < 2) {
        int t0 = 2 * j;
        x = (float)(off2[4 * v + t0 + 1] - off2[4 * v + t0]);
        y = (float)(off2[4 * v + t0 + 2] - off2[4 * v + t0 + 1]);
    }
    __hip_bfloat162 o;
    o.x = __float2bfloat16(x);
    o.y = __float2bfloat16(y);
    ((__hip_bfloat162*)(g + (size_t)v * KAGG))[256 + j] = o;
}

// ---------------------------------------------------------------- weight prep (once/call)
// W2[512 n][672 k] bf16: k<544 -> (Wcat @ w_ih) for n<384 (0 for h_n cols);
// k>=544 -> w_hh (0 for i_n cols). Gate cols n: 0..127 r, 128..255 z, 256..383 i_n, 384..511 h_n.
__global__ void k_prep2(const float* __restrict__ Wm, const float* __restrict__ bm,
                        const float* __restrict__ wih, const float* __restrict__ whh,
                        const float* __restrict__ bih, const float* __restrict__ bhh,
                        __hip_bfloat16* __restrict__ W2, float* __restrict__ bias512) {
    int idx = blockIdx.x * blockDim.x + threadIdx.x;
    if (idx < 512 * KTOT) {
        int n = idx / KTOT, k = idx % KTOT;
        float v = 0.0f;
        if (k < 544) {
            if (n < 384 && k < 516) {
                float s = 0.0f;
                if (k < 512) {
                    int t = k >> 7, d = k & 127;
                    const float* wr = Wm + (t << 14) + (d << 7);
#pragma unroll 4
                    for (int e = 0; e < 128; ++e) s += wr[e] * wih[e * 384 + n];
                } else {
                    const float* br = bm + ((k - 512) << 7);
#pragma unroll 4
                    for (int e = 0; e < 128; ++e) s += br[e] * wih[e * 384 + n];
                }
                v = s;
            }
        } else {
            int dd = k - 544;
            if (n < 256) v = whh[dd * 384 + n];
            else if (n >= 384) v = whh[dd * 384 + n - 128];
        }
        W2[idx] = __float2bfloat16(v);
    } else {
        int b = idx - 512 * KTOT;
        if (b < NGATES) {
            float v;
            if (b < 256) v = bih[b] + bhh[b];
            else if (b < 384) v = bih[b];
            else v = bhh[b - 128];
            bias512[b] = v;
        }
    }
}

// ---------------------------------------------------------------- per-type aggregation
__global__ __launch_bounds__(256) void k_agg(const __hip_bfloat16* __restrict__ hb,
                                             const int* __restrict__ off2,
                                             const int* __restrict__ csr_src,
                                             __hip_bfloat16* __restrict__ g) {
    int node = (blockIdx.x * blockDim.x + threadIdx.x) >> 6;
    int lane = threadIdx.x & 63;
    if (node >= NN) return;
    const __hip_bfloat162* hb2 = (const __hip_bfloat162*)hb;
    __hip_bfloat162* grow = (__hip_bfloat162*)(g + (size_t)node * KAGG);
    int b0 = off2[4 * node];
    int b1 = off2[4 * node + 1];
    int b2 = off2[4 * node + 2];
    int b3 = off2[4 * node + 3];
    int b4 = off2[4 * node + 4];
    int beg[5] = {b0, b1, b2, b3, b4};
#pragma unroll
    for (int t = 0; t < TT; ++t) {
        float ax = 0.0f, ay = 0.0f;
        int p = beg[t], e = beg[t + 1];
        for (; p + 1 < e; p += 2) {
            int s0 = csr_src[p];
            int s1 = csr_src[p + 1];
            __hip_bfloat162 v0 = hb2[(size_t)s0 * 64 + lane];
            __hip_bfloat162 v1 = hb2[(size_t)s1 * 64 + lane];
            ax += bf2f(v0.x) + bf2f(v1.x);
            ay += bf2f(v0.y) + bf2f(v1.y);
        }
        if (p < e) {
            int s0 = csr_src[p];
            __hip_bfloat162 v0 = hb2[(size_t)s0 * 64 + lane];
            ax += bf2f(v0.x);
            ay += bf2f(v0.y);
        }
        __hip_bfloat162 o;
        o.x = __float2bfloat16(ax);
        o.y = __float2bfloat16(ay);
        grow[t * 64 + lane] = o;
    }
}

// ---------------------------------------------------------------- fused step kernel (v4)
// gates[64x512] = [g(544)|h(128)] @ W2^T, composed weights, zero-blocks skipped.
// Counted-vmcnt pipeline (T3+T4): A (g rows; HBM/L3 latency) in a 4-buffer ring
// staged 3 chunks ahead; B (W2; L2-resident) in a 2-buffer ping-pong staged 1
// ahead. ONE raw s_barrier per chunk; all stage issues happen AFTER the barrier,
// so the barrier alone provides overwrite safety. vmcnt is counted, never a
// full drain mid-loop (issue order per iter: B(k+1) then A(k+3) =>
// steady-state vmcnt(1) for staging waves, vmcnt(0) for B-only waves whose
// sole outstanding op is the 1-iter-old L2-hit B load).
__global__ __launch_bounds__(512, 4) void k_step(const __hip_bfloat16* __restrict__ g,
                                                 const __hip_bfloat16* __restrict__ W2,
                                                 const float* __restrict__ bias512,
                                                 const __hip_bfloat16* __restrict__ hbi,
                                                 __hip_bfloat16* __restrict__ hbo) {
    __shared__ __align__(16) short As[4][64 * 32];    // 4 x 4 KB ring
    __shared__ __align__(16) short Bs[2][384 * 32];   // 2 x 24 KB ping-pong
    const int tid = threadIdx.x;
    const int lane = tid & 63;
    const int wave = tid >> 6;
    const int row0 = blockIdx.x * 64;
    const int quad = lane >> 4;
    const int m16 = lane & 15;
    // read-side swizzled k-offset (shorts): slot = quad ^ f(row), f(r) = (r ^ (r>>2)) & 3
    const int koff = ((quad ^ ((m16 ^ (m16 >> 2)) & 3)) << 3);
    const int brb = wave * 16 + m16;

    // A staging mapping (waves 0..3; slot = tid < 256): row = slot>>2,
    // LDS 16B slot (slot&3) sourced from global part (slot&3) ^ f(row)
    const int arow = tid >> 2;
    const int apart = (tid & 3) ^ ((arow ^ (arow >> 2)) & 3);
    int agrow = row0 + arow;
    if (agrow >= NN) agrow = NN - 1;
    const __hip_bfloat16* gA = g + (size_t)agrow * KAGG + apart * 8;
    const __hip_bfloat16* hA = hbi + (size_t)agrow * DD + apart * 8;

    auto stage_A = [&](int kc) {  // stage chunk kc into As[kc&3] (waves 0..3, 1 op/thread)
        if (wave < 4) {
            const glob_void* srcA = (kc < 17)
                                        ? (const glob_void*)(gA + kc * 32)
                                        : (const glob_void*)(hA + (kc - 17) * 32);
            __builtin_amdgcn_global_load_lds(srcA, (lds_void*)&As[kc & 3][(wave * 64) * 8],
                                             16, 0, 0);
        }
    };
    auto stage_B = [&](int kc) {  // stage chunk kc into Bs[kc&1] (all waves, 3 ops/thread)
#pragma unroll
        for (int i = 0; i < 3; ++i) {
            int s = tid + i * 512;
            int br = s >> 2;
            int bpart = (s & 3) ^ ((br ^ (br >> 2)) & 3);
            int grp = br >> 7;  // 0:r  1:z  2:(i_n for g-chunks / h_n for h-chunks)
            int within = br & 127;
            size_t n;
            int kk;
            if (kc < 17) {
                n = (size_t)(grp * 128 + within);
                kk = kc * 32 + bpart * 8;
            } else {
                n = (size_t)((grp < 2 ? grp * 128 : 384) + within);
                kk = 544 + (kc - 17) * 32 + bpart * 8;
            }
            __builtin_amdgcn_global_load_lds((const glob_void*)(W2 + n * KTOT + kk),
                                             (lds_void*)&Bs[kc & 1][(wave * 64 + i * 512) * 8],
                                             16, 0, 0);
        }
    };

    f32x4 acc[4][4];  // [row-tile][gate: r,z,in,hn]
#pragma unroll
    for (int rt = 0; rt < 4; ++rt)
#pragma unroll
        for (int c = 0; c < 4; ++c) acc[rt][c] = (f32x4){0.f, 0.f, 0.f, 0.f};

    // prologue: B(0) first, then A(0..2)  (issue order matters for the counted waits)
    stage_B(0);
    stage_A(0);
    stage_A(1);
    stage_A(2);

    for (int ki = 0; ki < 21; ++ki) {
        // counted wait: own-wave loads for chunk ki retired, younger prefetches stay in flight
        if (wave < 4) {
            if (ki == 0)
                asm volatile("s_waitcnt vmcnt(2)" ::: "memory");
            else if (ki <= 18)
                asm volatile("s_waitcnt vmcnt(1)" ::: "memory");
            else
                asm volatile("s_waitcnt vmcnt(0)" ::: "memory");
        } else {
            asm volatile("s_waitcnt vmcnt(0)" ::: "memory");
        }
        __builtin_amdgcn_s_barrier();
        asm volatile("" ::: "memory");
        __builtin_amdgcn_sched_barrier(0);

        // issue next prefetches (after barrier => overwrite-safe): B(ki+1), then A(ki+3)
        if (ki + 1 < 21) stage_B(ki + 1);
        if (ki + 3 < 21) stage_A(ki + 3);

        bf16x8 af[4];
#pragma unroll
        for (int rt = 0; rt < 4; ++rt)
            af[rt] = *(const bf16x8*)&As[ki & 3][(rt * 16 + m16) * 32 + koff];
        bf16x8 b0 = *(const bf16x8*)&Bs[ki & 1][(brb)*32 + koff];
        bf16x8 b1 = *(const bf16x8*)&Bs[ki & 1][(128 + brb) * 32 + koff];
        bf16x8 b2 = *(const bf16x8*)&Bs[ki & 1][(256 + brb) * 32 + koff];
#pragma unroll
        for (int rt = 0; rt < 4; ++rt)
            acc[rt][0] = __builtin_amdgcn_mfma_f32_16x16x32_bf16(af[rt], b0, acc[rt][0], 0, 0, 0);
#pragma unroll
        for (int rt = 0; rt < 4; ++rt)
            acc[rt][1] = __builtin_amdgcn_mfma_f32_16x16x32_bf16(af[rt], b1, acc[rt][1], 0, 0, 0);
        if (ki < 17) {
#pragma unroll
            for (int rt = 0; rt < 4; ++rt)
                acc[rt][2] = __builtin_amdgcn_mfma_f32_16x16x32_bf16(af[rt], b2, acc[rt][2], 0, 0, 0);
        } else {
#pragma unroll
            for (int rt = 0; rt < 4; ++rt)
                acc[rt][3] = __builtin_amdgcn_mfma_f32_16x16x32_bf16(af[rt], b2, acc[rt][3], 0, 0, 0);
        }
    }
    __syncthreads();  // all waves done reading Bs before it is reused as Ht

    // ---------------- epilogue: in-register GRU -> LDS -> full-line global write ----
    short* Ht = &Bs[0][0];  // 64x128 bf16 = 16 KB
    {
        const int d = wave * 16 + m16;
        const float brs = bias512[d];
        const float bzs = bias512[128 + d];
        const float bin_ = bias512[256 + d];
        const float bhn = bias512[384 + d];
#pragma unroll
        for (int rt = 0; rt < 4; ++rt) {
#pragma unroll
            for (int j = 0; j < 4; ++j) {
                const int rowl = rt * 16 + quad * 4 + j;
                const int grow = row0 + rowl;
                const float rs = acc[rt][0][j] + brs;
                const float zs = acc[rt][1][j] + bzs;
                const float inn = acc[rt][2][j] + bin_;
                const float hnn = acc[rt][3][j] + bhn;
                const float rr = 1.0f / (1.0f + __expf(-rs));
                const float zz = 1.0f / (1.0f + __expf(-zs));
                const float ng = tanhf(inn + rr * hnn);
                const float hv =
                    bf2f(hbi[(size_t)(grow < NN ? grow : NN - 1) * DD + d]);
                const float o = (1.0f - zz) * ng + zz * hv;
                __hip_bfloat16 ob = __float2bfloat16(o);
                Ht[rowl * 128 + d] = *(short*)&ob;
            }
        }
    }
    __syncthreads();
    {
        // 512 threads x 32 B contiguous -> fully-coalesced full-line stores
        const int row = tid >> 3;
        const int col = (tid & 7) * 16;
        if (row0 + row < NN) {
            bf16x8 v0 = *(const bf16x8*)&Ht[row * 128 + col];
            bf16x8 v1 = *(const bf16x8*)&Ht[row * 128 + col + 8];
            __hip_bfloat16* dstp = hbo + (size_t)(row0 + row) * DD + col;
            *(bf16x8*)dstp = v0;
            *(bf16x8*)(dstp + 8) = v1;
        }
    }
}

// ---------------------------------------------------------------- readout (n2g is sorted)
__global__ __launch_bounds__(128) void k_readout(const __hip_bfloat16* __restrict__ h,
                                                 const float* __restrict__ h1,
                                                 const int* __restrict__ n2g,
                                                 float* __restrict__ feats) {
    const int CHN = 64;
    int d = threadIdx.x;
    int v0 = blockIdx.x * CHN;
    if (v0 >= NN) return;
    int v1 = v0 + CHN;
    if (v1 > NN) v1 = NN;
    float sum = 0.0f;
    int cur = n2g[v0];
    for (int v = v0; v < v1; ++v) {
        int gph = n2g[v];
        if (gph != cur) {
            atomicAdd(&feats[cur * DD + d], sum);
            sum = 0.0f;
            cur = gph;
        }
        sum += bf2f(h[(size_t)v * DD + d]) + h1[(size_t)v * DD + d];
    }
    atomicAdd(&feats[cur * DD + d], sum);
}

// ---------------------------------------------------------------- classifier
__global__ void k_cls(const float* __restrict__ feats, const float* __restrict__ Wc,
                      const float* __restrict__ bc, float* __restrict__ out) {
    int t = threadIdx.x;
    if (t >= BB * 2) return;
    int b = t >> 1, c = t & 1;
    float s = bc[c];
    for (int d = 0; d < DD; ++d) s += feats[b * DD + d] * Wc[d * 2 + c];
    out[t] = s;
}

// ================================================================ launcher
extern "C" void kernel_launch(void* const* d_in, const int* in_sizes, int n_in, void* d_out,
                              int out_size, void* d_ws, size_t ws_size, hipStream_t stream) {
    const float* features = (const float*)d_in[0];
    const int* src = (const int*)d_in[1];
    const int* dst = (const int*)d_in[2];
    const int* etype = (const int*)d_in[3];
    const int* n2g = (const int*)d_in[4];
    const float* W_msg = (const float*)d_in[5];
    const float* b_msg = (const float*)d_in[6];
    const float* w_ih = (const float*)d_in[7];
    const float* b_ih = (const float*)d_in[8];
    const float* w_hh = (const float*)d_in[9];
    const float* b_hh = (const float*)d_in[10];
    const float* W_cls = (const float*)d_in[11];
    const float* b_cls = (const float*)d_in[12];
    float* out = (float*)d_out;

    char* ws = (char*)d_ws;
    size_t o = 0;
    auto alloc = [&](size_t bytes) {
        o = (o + 255) & ~(size_t)255;
        void* p = ws + o;
        o += bytes;
        return p;
    };
    int* deg2 = (int*)alloc(sizeof(int) * NBIN);
    int* off2 = (int*)alloc(sizeof(int) * (NBIN + 1));
    int* cursor = (int*)alloc(sizeof(int) * NBIN);
    int* bsum = (int*)alloc(sizeof(int) * NBLK);
    int* boff = (int*)alloc(sizeof(int) * NBLK);
    int* csr_src = (int*)alloc(sizeof(int) * EE);
    __hip_bfloat16* W2 = (__hip_bfloat16*)alloc(sizeof(__hip_bfloat16) * 512 * KTOT);
    float* bias512 = (float*)alloc(sizeof(float) * NGATES);
    float* hini = (float*)alloc(sizeof(float) * (size_t)NN * DD);
    __hip_bfloat16* hbfA = (__hip_bfloat16*)alloc(sizeof(__hip_bfloat16) * (size_t)NN * DD);
    __hip_bfloat16* hbfB = (__hip_bfloat16*)alloc(sizeof(__hip_bfloat16) * (size_t)NN * DD);
    __hip_bfloat16* g = (__hip_bfloat16*)alloc(sizeof(__hip_bfloat16) * (size_t)NN * KAGG);
    float* feats = (float*)alloc(sizeof(float) * BB * DD);

    // setup
    k_init_h<<<(NN * DD + 255) / 256, 256, 0, stream>>>(features, hini, hbfA);
    k_zero_i32<<<(NBIN + 255) / 256, 256, 0, stream>>>(deg2, NBIN);
    k_zero_f32<<<(BB * DD + 255) / 256, 256, 0, stream>>>(feats, BB * DD);
    k_hist<<<(EE + 255) / 256, 256, 0, stream>>>(dst, etype, deg2);
    k_scan_bsum<<<NBLK, 256, 0, stream>>>(deg2, bsum);
    k_scan_boff<<<1, 1024, 0, stream>>>(bsum, boff);
    k_scan_final<<<NBLK, 256, 0, stream>>>(deg2, boff, off2, cursor);
    k_fill<<<(EE + 255) / 256, 256, 0, stream>>>(dst, src, etype, cursor, csr_src);
    k_counts<<<(NN * 16 + 255) / 256, 256, 0, stream>>>(off2, g);
    {
        int prep_n = 512 * KTOT + NGATES;
        k_prep2<<<(prep_n + 255) / 256, 256, 0, stream>>>(W_msg, b_msg, w_ih, w_hh, b_ih,
                                                          b_hh, W2, bias512);
    }

    __hip_bfloat16* hbc = hbfA;
    __hip_bfloat16* hbx = hbfB;
    for (int s = 0; s < STEPS; ++s) {
        k_agg<<<(NN * 64 + 255) / 256, 256, 0, stream>>>(hbc, off2, csr_src, g);
        k_step<<<MT64, 512, 0, stream>>>(g, W2, bias512, hbc, hbx);
        __hip_bfloat16* tb = hbc; hbc = hbx; hbx = tb;
    }
    k_readout<<<(NN + 63) / 64, 128, 0, stream>>>(hbc, hini, n2g, feats);
    k_cls<<<1, 128, 0, stream>>>(feats, W_cls, b_cls, out);
}